// Round 1
// baseline (282.420 us; speedup 1.0000x reference)
//
#include <hip/hip_runtime.h>
#include <hip/hip_bf16.h>
#include <stdint.h>

typedef __bf16 bf16;
typedef __attribute__((ext_vector_type(8))) __bf16 bf16x8;
typedef __attribute__((ext_vector_type(4))) float f32x4;
typedef __attribute__((ext_vector_type(8))) unsigned short u16x8;

#define LDS_U32 __attribute__((address_space(3))) uint32_t
#define GLB_U32 const __attribute__((address_space(1))) uint32_t
#define GLOAD16(g, l) __builtin_amdgcn_global_load_lds((GLB_U32*)(g), (LDS_U32*)(l), 16, 0, 0)

// ---------------- f32 -> bf16 convert (vectorized float4 -> ushort4) ----------------
__global__ __launch_bounds__(256) void cvt_f32_to_bf16(const float* __restrict__ src,
                                                       bf16* __restrict__ dst, int n4) {
  int i = blockIdx.x * blockDim.x + threadIdx.x;
  int stride = gridDim.x * blockDim.x;
  for (int j = i; j < n4; j += stride) {
    float4 v = reinterpret_cast<const float4*>(src)[j];
    ushort4 o;
    o.x = __builtin_bit_cast(unsigned short, (bf16)v.x);
    o.y = __builtin_bit_cast(unsigned short, (bf16)v.y);
    o.z = __builtin_bit_cast(unsigned short, (bf16)v.z);
    o.w = __builtin_bit_cast(unsigned short, (bf16)v.w);
    reinterpret_cast<ushort4*>(dst)[j] = o;
  }
}

// ---------------- C = alpha * A @ B^T  (m97-style 128x128 tile, BK=32) ----------------
// A: [gridDim.y*128, K] bf16 row-major (K-contiguous), offset z*sA
// B: [gridDim.x*128, K] bf16 row-major (K-contiguous), offset z*sB
// EPI 0: bf16, C[z*sC + r*ldc + c]
// EPI 1: bf16, C[z*sC + c*ldc + r]   (transposed write)
// EPI 2: f32,  C[z*sC + r*ldc + c]
template <int EPI>
__global__ __launch_bounds__(256) void gemm_bt(const bf16* __restrict__ A,
                                               const bf16* __restrict__ B,
                                               void* __restrict__ Cp,
                                               int K, float alpha,
                                               long sA, long sB, long sC, int ldc) {
  constexpr int BK = 32;
  __shared__ bf16 As[128 * BK];
  __shared__ bf16 Bs[128 * BK];
  const long z = blockIdx.z;
  const bf16* Ab = A + z * sA + (long)(blockIdx.y * 128) * K;
  const bf16* Bb = B + z * sB + (long)(blockIdx.x * 128) * K;
  const int t = threadIdx.x;
  const int lane = t & 63;
  const int wave = t >> 6;
  const int wr = (wave >> 1) * 64;  // wave's row quadrant base
  const int wc = (wave & 1) * 64;   // wave's col quadrant base
  const int sr = t >> 2;            // staging row 0..63
  const int sc = (t & 3) * 8;       // staging col (bf16 elems), 16B per lane
  const int lrow = lane & 15;       // fragment row/col within 16
  const int lk = (lane >> 4) * 8;   // fragment k offset

  f32x4 acc[4][4] = {};

  for (int k0 = 0; k0 < K; k0 += BK) {
    // stage A(128x32) and B(128x32) via direct global->LDS, 16B/lane
    GLOAD16(Ab + (long)sr * K + k0 + sc, As + t * 8);
    GLOAD16(Ab + (long)(64 + sr) * K + k0 + sc, As + 2048 + t * 8);
    GLOAD16(Bb + (long)sr * K + k0 + sc, Bs + t * 8);
    GLOAD16(Bb + (long)(64 + sr) * K + k0 + sc, Bs + 2048 + t * 8);
    __syncthreads();  // drains vmcnt before reads

    bf16x8 aF[4], bF[4];
#pragma unroll
    for (int m = 0; m < 4; ++m)
      aF[m] = *reinterpret_cast<const bf16x8*>(&As[(wr + m * 16 + lrow) * BK + lk]);
#pragma unroll
    for (int n = 0; n < 4; ++n)
      bF[n] = *reinterpret_cast<const bf16x8*>(&Bs[(wc + n * 16 + lrow) * BK + lk]);
#pragma unroll
    for (int m = 0; m < 4; ++m)
#pragma unroll
      for (int n = 0; n < 4; ++n)
        acc[m][n] = __builtin_amdgcn_mfma_f32_16x16x32_bf16(aF[m], bF[n], acc[m][n], 0, 0, 0);
    __syncthreads();  // LDS reads done before next stage overwrites
  }

  // epilogue: C/D layout col = lane&15, row = (lane>>4)*4 + i  [m89/m91-verified]
  const int orow0 = blockIdx.y * 128 + wr + (lane >> 4) * 4;
  const int ocol0 = blockIdx.x * 128 + wc + lrow;
#pragma unroll
  for (int m = 0; m < 4; ++m)
#pragma unroll
    for (int n = 0; n < 4; ++n)
#pragma unroll
      for (int i = 0; i < 4; ++i) {
        const long r = orow0 + m * 16 + i;
        const long c = ocol0 + n * 16;
        const float v = acc[m][n][i] * alpha;
        if constexpr (EPI == 0)
          ((bf16*)Cp)[z * sC + r * ldc + c] = (bf16)v;
        else if constexpr (EPI == 1)
          ((bf16*)Cp)[z * sC + c * ldc + r] = (bf16)v;
        else
          ((float*)Cp)[z * sC + r * ldc + c] = v;
      }
}

// ---------------- row softmax, in place, rows of 2048 bf16 ----------------
__global__ __launch_bounds__(256) void softmax_rows(bf16* __restrict__ P) {
  const long row = blockIdx.x;
  bf16* p = P + row * 2048;
  const int t = threadIdx.x;
  const int lane = t & 63;
  const int wave = t >> 6;

  u16x8 raw = *reinterpret_cast<const u16x8*>(p + t * 8);
  float v[8];
#pragma unroll
  for (int j = 0; j < 8; ++j) {
    uint32_t bits = ((uint32_t)raw[j]) << 16;
    v[j] = __builtin_bit_cast(float, bits);
  }
  float m = v[0];
#pragma unroll
  for (int j = 1; j < 8; ++j) m = fmaxf(m, v[j]);
#pragma unroll
  for (int off = 32; off > 0; off >>= 1) m = fmaxf(m, __shfl_xor(m, off, 64));
  __shared__ float redm[4];
  __shared__ float reds[4];
  if (lane == 0) redm[wave] = m;
  __syncthreads();
  m = fmaxf(fmaxf(redm[0], redm[1]), fmaxf(redm[2], redm[3]));

  float s = 0.f;
#pragma unroll
  for (int j = 0; j < 8; ++j) {
    v[j] = __expf(v[j] - m);
    s += v[j];
  }
#pragma unroll
  for (int off = 32; off > 0; off >>= 1) s += __shfl_xor(s, off, 64);
  if (lane == 0) reds[wave] = s;
  __syncthreads();
  s = reds[0] + reds[1] + reds[2] + reds[3];
  const float inv = 1.f / s;

  u16x8 o;
#pragma unroll
  for (int j = 0; j < 8; ++j) o[j] = __builtin_bit_cast(unsigned short, (bf16)(v[j] * inv));
  *reinterpret_cast<u16x8*>(p + t * 8) = o;
}

// ---------------- launch ----------------
extern "C" void kernel_launch(void* const* d_in, const int* in_sizes, int n_in,
                              void* d_out, int out_size, void* d_ws, size_t ws_size,
                              hipStream_t stream) {
  const float* q = (const float*)d_in[0];
  const float* wq = (const float*)d_in[1];
  const float* wk = (const float*)d_in[2];
  const float* wv = (const float*)d_in[3];
  const float* wo = (const float*)d_in[4];
  float* out = (float*)d_out;

  constexpr int B = 4, S = 2048, D = 1024;
  constexpr long SD = (long)S * D;  // 2,097,152
  constexpr long SS = (long)S * S;  // 4,194,304
  constexpr long DD = (long)D * D;  // 1,048,576

  bf16* wsb = (bf16*)d_ws;
  bf16* qb = wsb;            // B*SD
  bf16* wqb = qb + B * SD;   // DD
  bf16* wkb = wqb + DD;
  bf16* wvb = wkb + DD;
  bf16* wob = wvb + DD;
  bf16* Qb = wob + DD;       // B*SD
  bf16* Kb = Qb + B * SD;    // B*SD
  bf16* Vt = Kb + B * SD;    // B*SD, layout [B][D][S]
  bf16* P = Vt + B * SD;     // B*SS (scores then attn probs, in place)
  bf16* X = P + B * SS;      // B*SD, layout [B][D][S] == bugged buffer

  cvt_f32_to_bf16<<<2048, 256, 0, stream>>>(q, qb, (int)(B * SD / 4));
  cvt_f32_to_bf16<<<256, 256, 0, stream>>>(wq, wqb, (int)(DD / 4));
  cvt_f32_to_bf16<<<256, 256, 0, stream>>>(wk, wkb, (int)(DD / 4));
  cvt_f32_to_bf16<<<256, 256, 0, stream>>>(wv, wvb, (int)(DD / 4));
  cvt_f32_to_bf16<<<256, 256, 0, stream>>>(wo, wob, (int)(DD / 4));

  // Q = qb @ wq^T ; K = qb @ wk^T   (per batch: M=2048, N=1024, K=1024)
  gemm_bt<0><<<dim3(D / 128, S / 128, B), 256, 0, stream>>>(qb, wqb, Qb, D, 1.f, SD, 0, SD, D);
  gemm_bt<0><<<dim3(D / 128, S / 128, B), 256, 0, stream>>>(qb, wkb, Kb, D, 1.f, SD, 0, SD, D);
  // Vt[b][e][s] = (qb @ wv^T)[b][s][e]  (transposed epilogue)
  gemm_bt<1><<<dim3(D / 128, S / 128, B), 256, 0, stream>>>(qb, wvb, Vt, D, 1.f, SD, 0, SD, S);
  // scores: P[b][i][j] = Q[b,i,:]·K[b,j,:] / 8   (M=N=2048, K=1024)
  gemm_bt<0><<<dim3(S / 128, S / 128, B), 256, 0, stream>>>(Qb, Kb, P, D, 0.125f, SD, SD, SS, S);
  softmax_rows<<<B * S, 256, 0, stream>>>(P);
  // X[b][e][i] = sum_j P[b][i][j] * Vt[b][e][j]  (M=2048, N=1024, K=2048, transposed write)
  gemm_bt<1><<<dim3(D / 128, S / 128, B), 256, 0, stream>>>(P, Vt, X, S, 1.f, SS, SD, SD, S);
  // out = Xview[B*S, D] @ wo^T  -> f32   (bug folded: X flat IS the transposed-reshape buffer)
  gemm_bt<2><<<dim3(D / 128, S / 128, B), 256, 0, stream>>>(X, wob, out, D, 1.f, SD, 0, SD, D);
}

// Round 2
// 260.026 us; speedup vs baseline: 1.0861x; 1.0861x over previous
//
#include <hip/hip_runtime.h>
#include <hip/hip_bf16.h>
#include <stdint.h>

typedef __bf16 bf16;
typedef __attribute__((ext_vector_type(8))) __bf16 bf16x8;
typedef __attribute__((ext_vector_type(4))) float f32x4;
typedef __attribute__((ext_vector_type(8))) unsigned short u16x8;

#define LDS_U32 __attribute__((address_space(3))) uint32_t
#define GLB_U32 const __attribute__((address_space(1))) uint32_t
#define GLOAD16(g, l) __builtin_amdgcn_global_load_lds((GLB_U32*)(g), (LDS_U32*)(l), 16, 0, 0)

// ---------------- f32 -> bf16 convert ----------------
__global__ __launch_bounds__(256) void cvt_f32_to_bf16(const float* __restrict__ src,
                                                       bf16* __restrict__ dst, int n4) {
  int i = blockIdx.x * blockDim.x + threadIdx.x;
  int stride = gridDim.x * blockDim.x;
  for (int j = i; j < n4; j += stride) {
    float4 v = reinterpret_cast<const float4*>(src)[j];
    ushort4 o;
    o.x = __builtin_bit_cast(unsigned short, (bf16)v.x);
    o.y = __builtin_bit_cast(unsigned short, (bf16)v.y);
    o.z = __builtin_bit_cast(unsigned short, (bf16)v.z);
    o.w = __builtin_bit_cast(unsigned short, (bf16)v.w);
    reinterpret_cast<ushort4*>(dst)[j] = o;
  }
}

// ================= 256x256 8-phase GEMM, C = alpha * A @ B^T =================
// A: [M,K] bf16 K-major (+ z*sA), B: [N,K] bf16 K-major (+ z*sB). BK=64.
// 512 threads = 8 waves (2 row x 4 col), per-wave 128x64 output, acc[8][4].
// LDS: 8 half-tile slots x 16KB = 128KB. Slot layout per parity p=T&1:
//   p*65536 + {A-lo:0, A-hi:16384, B-lo:32768, B-hi:49152}
// Half-tile (128r x 64c bf16) st_16x32-subtiled: g = ((r>>4)*2+(c>>5))*1024
//   + (r&15)*64 + (c&31)*2 ; swz byte f = g ^ (((g>>9)&1)<<5).
// Staging: linear LDS dest (lane*16) + inverse-swizzled per-lane global src.
// Pipeline: phase0/1 issue A(T+1) (into T-1's dead A slots); phase2/3 issue
// B(T+2) (into T's B slots, dead after phase0 since bF is reg-resident).
// Boundary: vmcnt(4) (B(T+2) in flight), raw s_barrier. Never vmcnt(0) mid-loop.
// EPI 0: bf16 C[z*sC + r*ldc + c]; 1: bf16 C[z*sC + c*ldc + r] (transposed);
// EPI 2: f32 C[r*ldc + c]; 3: fused QKV routing (hardcoded shapes).
template <int EPI>
__global__ __launch_bounds__(512, 2) void g256(const bf16* __restrict__ A,
                                               const bf16* __restrict__ Bm,
                                               void* __restrict__ Cp,
                                               int K, float alpha,
                                               long sA, long sB, long sC, int ldc) {
  __shared__ bf16 smem_[65536];  // 128 KiB
  const long z = blockIdx.z;
  const int t = threadIdx.x;
  const int l = t & 63;
  const int w = t >> 6;
  const int wr = (w >> 2) * 128;  // wave row base within 256
  const int wc = (w & 3) * 64;    // wave col base within 256
  const int NT = K >> 6;

  const bf16* Ab = A + z * sA + (long)(blockIdx.y * 256) * K;
  const bf16* Bb = Bm + z * sB + (long)(blockIdx.x * 256) * K;

  // ---- staging inverse map for this thread's chunk q = t (and q+512 = +64 rows)
  uint32_t loc = (uint32_t)t * 16u;
  uint32_t g0 = loc ^ (((loc >> 9) & 1u) << 5);
  const int r0 = (int)(((g0 >> 10) >> 1) * 16 + ((g0 >> 6) & 15));
  const int c0 = (int)(((g0 >> 10) & 1) * 32 + ((g0 & 63) >> 1));
  const long r0K = (long)r0 * K;
  const long ld64 = (long)64 * K;
  const long ld128 = (long)128 * K;
  const uint32_t stage_dst = (uint32_t)t * 16u;

  // ---- per-lane swizzled fragment read offset (bytes within a half-tile)
  uint32_t lo_ = (uint32_t)((l & 15) * 64 + (l >> 4) * 16);
  const uint32_t lane_off = lo_ ^ (((lo_ >> 9) & 1u) << 5);
  const uint32_t aRegion = (uint32_t)(wr >> 7) * 16384u;           // A half this wave reads
  const uint32_t bRegion = 32768u + (uint32_t)(wc >> 7) * 16384u;  // B half this wave reads
  const int bR0 = (wc & 64) >> 4;                                  // B subtile-row base (0 or 4)

  // stage one half-tile: 2 x global_load_lds per thread
  auto STAGE = [&](const bf16* mat, int halfJ, int tIdx, uint32_t isBoff) {
    uint32_t dst = ((uint32_t)(tIdx & 1)) * 65536u + isBoff + (uint32_t)halfJ * 16384u + stage_dst;
    const bf16* src = mat + (halfJ ? ld128 : 0) + r0K + (long)(tIdx * 64) + c0;
    GLOAD16(src, smem_ + (dst >> 1));
    GLOAD16(src + ld64, smem_ + ((dst + 8192u) >> 1));
  };

  f32x4 acc[8][4] = {};

  // ---- prologue: A(0), B(0), B(1); wait A(0)+B(0) landed (B(1) = 4 loads in flight)
  STAGE(Ab, 0, 0, 0u);
  STAGE(Ab, 1, 0, 0u);
  STAGE(Bb, 0, 0, 32768u);
  STAGE(Bb, 1, 0, 32768u);
  if (NT > 1) {
    STAGE(Bb, 0, 1, 32768u);
    STAGE(Bb, 1, 1, 32768u);
    asm volatile("s_waitcnt vmcnt(4)" ::: "memory");
  } else {
    asm volatile("s_waitcnt vmcnt(0)" ::: "memory");
  }
  __builtin_amdgcn_s_barrier();

#define PHASE_BODY(ph)                                                                     \
  {                                                                                        \
    bf16x8 aF[2][2];                                                                       \
    _Pragma("unroll") for (int mi = 0; mi < 2; ++mi)                                       \
    _Pragma("unroll") for (int kkI = 0; kkI < 2; ++kkI)                                    \
      aF[mi][kkI] = *(const bf16x8*)(smem_ +                                               \
          ((pbase + aRegion + (uint32_t)((((ph)*2 + mi) * 2 + kkI) << 10) + lane_off) >> 1)); \
    if ((ph) < 2) { if (T + 1 < NT) STAGE(Ab, (ph), T + 1, 0u); }                          \
    else          { if (T + 2 < NT) STAGE(Bb, (ph) - 2, T + 2, 32768u); }                  \
    __builtin_amdgcn_s_barrier();                                                          \
    __builtin_amdgcn_s_setprio(1);                                                         \
    _Pragma("unroll") for (int mi = 0; mi < 2; ++mi)                                       \
    _Pragma("unroll") for (int n = 0; n < 4; ++n)                                          \
    _Pragma("unroll") for (int kkI = 0; kkI < 2; ++kkI)                                    \
      acc[(ph)*2 + mi][n] = __builtin_amdgcn_mfma_f32_16x16x32_bf16(                       \
          aF[mi][kkI], bFr[n][kkI], acc[(ph)*2 + mi][n], 0, 0, 0);                         \
    __builtin_amdgcn_s_setprio(0);                                                         \
  }

  for (int T = 0; T < NT; ++T) {
    const uint32_t pbase = (uint32_t)(T & 1) * 65536u;
    // phase 0: read all bF (8 reads), aF m0,1 (4 reads)
    bf16x8 bFr[4][2];
#pragma unroll
    for (int n = 0; n < 4; ++n)
#pragma unroll
      for (int kkI = 0; kkI < 2; ++kkI)
        bFr[n][kkI] = *(const bf16x8*)(smem_ +
            ((pbase + bRegion + (uint32_t)(((bR0 + n) * 2 + kkI) << 10) + lane_off) >> 1));
    PHASE_BODY(0)
    __builtin_amdgcn_s_barrier();
    PHASE_BODY(1)
    __builtin_amdgcn_s_barrier();
    PHASE_BODY(2)
    __builtin_amdgcn_s_barrier();
    PHASE_BODY(3)
    // boundary: A(T+1),B(T+1) must be landed; B(T+2) (4 loads) stays in flight
    if (T + 2 < NT) asm volatile("s_waitcnt vmcnt(4)" ::: "memory");
    else            asm volatile("s_waitcnt vmcnt(0)" ::: "memory");
    __builtin_amdgcn_s_barrier();
  }
#undef PHASE_BODY

  // ---- epilogue: C/D layout col = lane&15, row = (lane>>4)*4 + i
  const int orow0 = blockIdx.y * 256 + wr + (l >> 4) * 4;
  const int ocol0 = blockIdx.x * 256 + wc + (l & 15);
#pragma unroll
  for (int m = 0; m < 8; ++m)
#pragma unroll
    for (int n = 0; n < 4; ++n)
#pragma unroll
      for (int i = 0; i < 4; ++i) {
        const long r = orow0 + m * 16 + i;
        const long c = ocol0 + n * 16;
        const float v = acc[m][n][i] * alpha;
        if constexpr (EPI == 0) {
          ((bf16*)Cp)[z * sC + r * ldc + c] = (bf16)v;
        } else if constexpr (EPI == 1) {
          ((bf16*)Cp)[z * sC + c * ldc + r] = (bf16)v;
        } else if constexpr (EPI == 2) {
          ((float*)Cp)[r * ldc + c] = v;
        } else {
          // fused QKV epilogue: A rows r in [0,8192) = b*2048+s; cols c in [0,3072)
          bf16* Qb = (bf16*)Cp;
          bf16* Kb = Qb + 8388608;  // 8192*1024
          bf16* Vt = Kb + 8388608;
          if (c < 1024) Qb[r * 1024 + c] = (bf16)v;
          else if (c < 2048) Kb[r * 1024 + (c - 1024)] = (bf16)v;
          else Vt[(r >> 11) * 2097152 + (c - 2048) * 2048 + (r & 2047)] = (bf16)v;
        }
      }
}

// ---------------- row softmax, in place, rows of 2048 bf16 ----------------
__global__ __launch_bounds__(256) void softmax_rows(bf16* __restrict__ P) {
  const long row = blockIdx.x;
  bf16* p = P + row * 2048;
  const int t = threadIdx.x;
  const int lane = t & 63;
  const int wave = t >> 6;

  u16x8 raw = *reinterpret_cast<const u16x8*>(p + t * 8);
  float v[8];
#pragma unroll
  for (int j = 0; j < 8; ++j) {
    uint32_t bits = ((uint32_t)raw[j]) << 16;
    v[j] = __builtin_bit_cast(float, bits);
  }
  float m = v[0];
#pragma unroll
  for (int j = 1; j < 8; ++j) m = fmaxf(m, v[j]);
#pragma unroll
  for (int off = 32; off > 0; off >>= 1) m = fmaxf(m, __shfl_xor(m, off, 64));
  __shared__ float redm[4];
  __shared__ float reds[4];
  if (lane == 0) redm[wave] = m;
  __syncthreads();
  m = fmaxf(fmaxf(redm[0], redm[1]), fmaxf(redm[2], redm[3]));

  float s = 0.f;
#pragma unroll
  for (int j = 0; j < 8; ++j) {
    v[j] = __expf(v[j] - m);
    s += v[j];
  }
#pragma unroll
  for (int off = 32; off > 0; off >>= 1) s += __shfl_xor(s, off, 64);
  if (lane == 0) reds[wave] = s;
  __syncthreads();
  s = reds[0] + reds[1] + reds[2] + reds[3];
  const float inv = 1.f / s;

  u16x8 o;
#pragma unroll
  for (int j = 0; j < 8; ++j) o[j] = __builtin_bit_cast(unsigned short, (bf16)(v[j] * inv));
  *reinterpret_cast<u16x8*>(p + t * 8) = o;
}

// ---------------- launch ----------------
extern "C" void kernel_launch(void* const* d_in, const int* in_sizes, int n_in,
                              void* d_out, int out_size, void* d_ws, size_t ws_size,
                              hipStream_t stream) {
  const float* q = (const float*)d_in[0];
  const float* wq = (const float*)d_in[1];
  const float* wk = (const float*)d_in[2];
  const float* wv = (const float*)d_in[3];
  const float* wo = (const float*)d_in[4];
  float* out = (float*)d_out;

  constexpr int B = 4, S = 2048, D = 1024;
  constexpr long SD = (long)S * D;  // 2,097,152
  constexpr long SS = (long)S * S;  // 4,194,304
  constexpr long DD = (long)D * D;  // 1,048,576

  bf16* wsb = (bf16*)d_ws;
  bf16* qb = wsb;             // B*SD
  bf16* W3 = qb + B * SD;     // 3*DD  (wq;wk;wv stacked rows)
  bf16* wob = W3 + 3 * DD;    // DD
  bf16* Qb = wob + DD;        // B*SD
  bf16* Kb = Qb + B * SD;     // B*SD
  bf16* Vt = Kb + B * SD;     // B*SD, layout [B][D][S]
  bf16* P = Vt + B * SD;      // B*SS
  bf16* X = P + B * SS;       // B*SD, layout [B][D][S] == bugged buffer

  cvt_f32_to_bf16<<<2048, 256, 0, stream>>>(q, qb, (int)(B * SD / 4));
  cvt_f32_to_bf16<<<256, 256, 0, stream>>>(wq, W3, (int)(DD / 4));
  cvt_f32_to_bf16<<<256, 256, 0, stream>>>(wk, W3 + DD, (int)(DD / 4));
  cvt_f32_to_bf16<<<256, 256, 0, stream>>>(wv, W3 + 2 * DD, (int)(DD / 4));
  cvt_f32_to_bf16<<<256, 256, 0, stream>>>(wo, wob, (int)(DD / 4));

  // fused QKV: [8192 x 1024] @ [3072 x 1024]^T -> Qb, Kb, Vt(transposed)
  g256<3><<<dim3(12, 32, 1), 512, 0, stream>>>(qb, W3, Qb, D, 1.f, 0, 0, 0, 0);
  // scores: P[b][i][j] = Q.K/8  (per batch 2048x2048, K=1024)
  g256<0><<<dim3(8, 8, B), 512, 0, stream>>>(Qb, Kb, P, D, 0.125f, SD, SD, SS, S);
  softmax_rows<<<B * S, 256, 0, stream>>>(P);
  // X[b][e][i] = sum_j P[b][i][j] * Vt[b][e][j]  (M=2048, N=1024, K=2048)
  g256<1><<<dim3(4, 8, B), 512, 0, stream>>>(P, Vt, X, S, 1.f, SS, SD, SD, S);
  // out = Xflat[8192x1024] @ wo^T -> f32
  g256<2><<<dim3(4, 32, 1), 512, 0, stream>>>(X, wob, out, D, 1.f, 0, 0, 0, D);
}

// Round 3
// 257.290 us; speedup vs baseline: 1.0977x; 1.0106x over previous
//
#include <hip/hip_runtime.h>
#include <hip/hip_bf16.h>
#include <stdint.h>

typedef __bf16 bf16;
typedef __attribute__((ext_vector_type(8))) __bf16 bf16x8;
typedef __attribute__((ext_vector_type(4))) float f32x4;
typedef __attribute__((ext_vector_type(8))) unsigned short u16x8;

#define LDS_U32 __attribute__((address_space(3))) uint32_t
#define GLB_U32 const __attribute__((address_space(1))) uint32_t
#define GLOAD16(g, l) __builtin_amdgcn_global_load_lds((GLB_U32*)(g), (LDS_U32*)(l), 16, 0, 0)

// ---------------- f32 -> bf16 convert ----------------
__global__ __launch_bounds__(256) void cvt_f32_to_bf16(const float* __restrict__ src,
                                                       bf16* __restrict__ dst, int n4) {
  int i = blockIdx.x * blockDim.x + threadIdx.x;
  int stride = gridDim.x * blockDim.x;
  for (int j = i; j < n4; j += stride) {
    float4 v = reinterpret_cast<const float4*>(src)[j];
    ushort4 o;
    o.x = __builtin_bit_cast(unsigned short, (bf16)v.x);
    o.y = __builtin_bit_cast(unsigned short, (bf16)v.y);
    o.z = __builtin_bit_cast(unsigned short, (bf16)v.z);
    o.w = __builtin_bit_cast(unsigned short, (bf16)v.w);
    reinterpret_cast<ushort4*>(dst)[j] = o;
  }
}

// ================= 256x256 8-phase GEMM, C = alpha * A @ B^T =================
// A: [M,K] bf16 K-major (+ z*sA), B: [N,K] bf16 K-major (+ z*sB). BK=64.
// 512 threads = 8 waves (2 row x 4 col), per-wave 128x64 output, acc[8][4].
// LDS: 2 parities x {A 32KB, B 32KB} = 128KB. Parity P slots at P*65536:
//   A units 0..3 (64 rows x 64 k each, 8KB) at unit*8192; B at +32768 same.
// st_16x32 swizzle: within a 64-row unit, subtile g = (r>>4)*2+(c>>5) (1KB),
//   byte = g*1024 + (r&15)*64 + (c&31)*2, f = byte ^ (((byte>>9)&1)<<5).
// Staging: linear LDS dest (t*16) + inverse-swizzled per-lane global (r0,c0).
// Deep ring (prefetch distance 2, m201-equivalent):
//   ph0: stage A(T+1) units{1,3}   (freed by quads 2,3 of tile T-1)
//   ph1: stage B(T+2) units{0,1}   (B parity T&1 freed after ph0 bF reads)
//   ph2: stage A(T+2) units{0,2}   (freed by quads 0,1 = ph0/ph1 of tile T)
//   ph3: stage B(T+2) units{2,3}
//   boundary: vmcnt(6) -> retires {A(T+1),B(T+1)}, leaves {B(T+2),A(T+2)p1}.
// Each staged unit is >=2 barriers after its last reader; gload writes reach
// LDS ~HBM-latency after issue, so earlier-issued ds_reads cannot be overtaken.
// EPI 0: bf16 C[z*sC + r*ldc + c]; 2: f32 C[r*ldc + c]; 3: fused QKV routing.
template <int EPI>
__global__ __launch_bounds__(512, 2) void g256(const bf16* __restrict__ A,
                                               const bf16* __restrict__ Bm,
                                               void* __restrict__ Cp,
                                               int K, float alpha,
                                               long sA, long sB, long sC, int ldc) {
  __shared__ bf16 smem_[65536];  // 128 KiB
  const long z = blockIdx.z;
  const int t = threadIdx.x;
  const int l = t & 63;
  const int w = t >> 6;
  const int wr = (w >> 2) * 128;  // wave row base within 256
  const int wc = (w & 3) * 64;    // wave col base within 256
  const int NT = K >> 6;

  const bf16* Ab = A + z * sA + (long)(blockIdx.y * 256) * K;
  const bf16* Bb = Bm + z * sB + (long)(blockIdx.x * 256) * K;

  // ---- staging inverse map: thread t covers swizzled bytes [t*16, t*16+16)
  // of one 8KB 64-row unit; (r0,c0) = source row/col within the unit.
  uint32_t loc = (uint32_t)t * 16u;
  uint32_t g0 = loc ^ (((loc >> 9) & 1u) << 5);
  const int r0 = (int)(((g0 >> 10) >> 1) * 16 + ((g0 >> 6) & 15));  // 0..63
  const int c0 = (int)(((g0 >> 10) & 1) * 32 + ((g0 & 63) >> 1));   // 0..63

  // ---- per-lane swizzled fragment read offset (bytes within a 1KB subtile grid)
  uint32_t lo_ = (uint32_t)((l & 15) * 64 + (l >> 4) * 16);
  const uint32_t lane_off = lo_ ^ (((lo_ >> 9) & 1u) << 5);
  const uint32_t aRegion = (uint32_t)(wr >> 7) * 16384u;           // this wave's A half
  const uint32_t bRegion = 32768u + (uint32_t)(wc >> 7) * 16384u;  // this wave's B half
  const int bR0 = (wc & 64) >> 4;  // B subtile row-group base (0 or 4)

  // stage one 64-row unit (1 x global_load_lds, 512 threads cover 8KB)
  auto STAGE1 = [&](const bf16* mat, int unit, int tile, uint32_t isB) {
    uint32_t dst = ((uint32_t)(tile & 1)) * 65536u + isB + (uint32_t)unit * 8192u + (uint32_t)t * 16u;
    const bf16* src = mat + (long)(unit * 64 + r0) * K + tile * 64 + c0;
    GLOAD16(src, smem_ + (dst >> 1));
  };

  f32x4 acc[8][4] = {};

  // ---- prologue: A(0) full, B(0) full, A(1) p1 {0,2}, B(1) full = 14 loads
  STAGE1(Ab, 0, 0, 0u); STAGE1(Ab, 1, 0, 0u); STAGE1(Ab, 2, 0, 0u); STAGE1(Ab, 3, 0, 0u);
  STAGE1(Bb, 0, 0, 32768u); STAGE1(Bb, 1, 0, 32768u); STAGE1(Bb, 2, 0, 32768u); STAGE1(Bb, 3, 0, 32768u);
  if (NT > 1) {
    STAGE1(Ab, 0, 1, 0u); STAGE1(Ab, 2, 1, 0u);
    STAGE1(Bb, 0, 1, 32768u); STAGE1(Bb, 1, 1, 32768u); STAGE1(Bb, 2, 1, 32768u); STAGE1(Bb, 3, 1, 32768u);
    asm volatile("s_waitcnt vmcnt(6)" ::: "memory");  // A(0),B(0) landed
  } else {
    asm volatile("s_waitcnt vmcnt(0)" ::: "memory");
  }
  __builtin_amdgcn_s_barrier();

  for (int T = 0; T < NT; ++T) {
    const uint32_t pbase = (uint32_t)(T & 1) * 65536u;
    bf16x8 bFr[4][2];

    // ---------- phase 0: all bF (8) + aF quad0 (4); stage A(T+1) p2 ----------
#pragma unroll
    for (int n = 0; n < 4; ++n)
#pragma unroll
      for (int kk = 0; kk < 2; ++kk)
        bFr[n][kk] = *(const bf16x8*)(smem_ +
            ((pbase + bRegion + (uint32_t)(((bR0 + n) * 2 + kk) << 10) + lane_off) >> 1));
    {
      bf16x8 aF[2][2];
#pragma unroll
      for (int mi = 0; mi < 2; ++mi)
#pragma unroll
        for (int kk = 0; kk < 2; ++kk)
          aF[mi][kk] = *(const bf16x8*)(smem_ +
              ((pbase + aRegion + (uint32_t)(((0 * 2 + mi) * 2 + kk) << 10) + lane_off) >> 1));
      if (T + 1 < NT) { STAGE1(Ab, 1, T + 1, 0u); STAGE1(Ab, 3, T + 1, 0u); }
      asm volatile("s_waitcnt lgkmcnt(8)" ::: "memory");
      __builtin_amdgcn_s_barrier();
      __builtin_amdgcn_s_setprio(1);
#pragma unroll
      for (int mi = 0; mi < 2; ++mi)
#pragma unroll
        for (int n = 0; n < 4; ++n)
#pragma unroll
          for (int kk = 0; kk < 2; ++kk)
            acc[0 * 2 + mi][n] = __builtin_amdgcn_mfma_f32_16x16x32_bf16(
                aF[mi][kk], bFr[n][kk], acc[0 * 2 + mi][n], 0, 0, 0);
      __builtin_amdgcn_s_setprio(0);
      __builtin_amdgcn_s_barrier();
    }

#define PHASE(ph, STAGE_STMT)                                                              \
    {                                                                                      \
      bf16x8 aF[2][2];                                                                     \
      _Pragma("unroll") for (int mi = 0; mi < 2; ++mi)                                     \
      _Pragma("unroll") for (int kk = 0; kk < 2; ++kk)                                     \
        aF[mi][kk] = *(const bf16x8*)(smem_ +                                              \
            ((pbase + aRegion + (uint32_t)((((ph) * 2 + mi) * 2 + kk) << 10) + lane_off) >> 1)); \
      STAGE_STMT                                                                           \
      __builtin_amdgcn_s_barrier();                                                        \
      __builtin_amdgcn_s_setprio(1);                                                       \
      _Pragma("unroll") for (int mi = 0; mi < 2; ++mi)                                     \
      _Pragma("unroll") for (int n = 0; n < 4; ++n)                                        \
      _Pragma("unroll") for (int kk = 0; kk < 2; ++kk)                                     \
        acc[(ph) * 2 + mi][n] = __builtin_amdgcn_mfma_f32_16x16x32_bf16(                   \
            aF[mi][kk], bFr[n][kk], acc[(ph) * 2 + mi][n], 0, 0, 0);                       \
      __builtin_amdgcn_s_setprio(0);                                                       \
    }

    // ---------- phase 1 ----------
    PHASE(1, if (T + 2 < NT) { STAGE1(Bb, 0, T + 2, 32768u); STAGE1(Bb, 1, T + 2, 32768u); })
    __builtin_amdgcn_s_barrier();
    // ---------- phase 2 ----------
    PHASE(2, if (T + 2 < NT) { STAGE1(Ab, 0, T + 2, 0u); STAGE1(Ab, 2, T + 2, 0u); })
    __builtin_amdgcn_s_barrier();
    // ---------- phase 3 + boundary ----------
    PHASE(3, if (T + 2 < NT) { STAGE1(Bb, 2, T + 2, 32768u); STAGE1(Bb, 3, T + 2, 32768u); })
    if (T + 2 < NT) asm volatile("s_waitcnt vmcnt(6)" ::: "memory");
    else            asm volatile("s_waitcnt vmcnt(0)" ::: "memory");
    __builtin_amdgcn_s_barrier();
#undef PHASE
  }

  // ---- epilogue: C/D layout col = lane&15, row = (lane>>4)*4 + i
  const int orow0 = blockIdx.y * 256 + wr + (l >> 4) * 4;
  const int ocol0 = blockIdx.x * 256 + wc + (l & 15);
#pragma unroll
  for (int m = 0; m < 8; ++m)
#pragma unroll
    for (int n = 0; n < 4; ++n)
#pragma unroll
      for (int i = 0; i < 4; ++i) {
        const long r = orow0 + m * 16 + i;
        const long c = ocol0 + n * 16;
        const float v = acc[m][n][i] * alpha;
        if constexpr (EPI == 0) {
          ((bf16*)Cp)[z * sC + r * ldc + c] = (bf16)v;
        } else if constexpr (EPI == 2) {
          ((float*)Cp)[r * ldc + c] = v;
        } else {
          // fused QKV epilogue: rows r = b*2048+s in [0,8192); cols c in [0,3072)
          bf16* Qb = (bf16*)Cp;
          bf16* Kb = Qb + 8388608;  // 8192*1024
          bf16* Vt = Kb + 8388608;
          if (c < 1024) Qb[r * 1024 + c] = (bf16)v;
          else if (c < 2048) Kb[r * 1024 + (c - 1024)] = (bf16)v;
          else Vt[(r >> 11) * 2097152 + (c - 2048) * 2048 + (r & 2047)] = (bf16)v;
        }
      }
}

// ---------------- row softmax, in place, rows of 2048 bf16 ----------------
__global__ __launch_bounds__(256) void softmax_rows(bf16* __restrict__ P) {
  const long row = blockIdx.x;
  bf16* p = P + row * 2048;
  const int t = threadIdx.x;
  const int lane = t & 63;
  const int wave = t >> 6;

  u16x8 raw = *reinterpret_cast<const u16x8*>(p + t * 8);
  float v[8];
#pragma unroll
  for (int j = 0; j < 8; ++j) {
    uint32_t bits = ((uint32_t)raw[j]) << 16;
    v[j] = __builtin_bit_cast(float, bits);
  }
  float m = v[0];
#pragma unroll
  for (int j = 1; j < 8; ++j) m = fmaxf(m, v[j]);
#pragma unroll
  for (int off = 32; off > 0; off >>= 1) m = fmaxf(m, __shfl_xor(m, off, 64));
  __shared__ float redm[4];
  __shared__ float reds[4];
  if (lane == 0) redm[wave] = m;
  __syncthreads();
  m = fmaxf(fmaxf(redm[0], redm[1]), fmaxf(redm[2], redm[3]));

  float s = 0.f;
#pragma unroll
  for (int j = 0; j < 8; ++j) {
    v[j] = __expf(v[j] - m);
    s += v[j];
  }
#pragma unroll
  for (int off = 32; off > 0; off >>= 1) s += __shfl_xor(s, off, 64);
  if (lane == 0) reds[wave] = s;
  __syncthreads();
  s = reds[0] + reds[1] + reds[2] + reds[3];
  const float inv = 1.f / s;

  u16x8 o;
#pragma unroll
  for (int j = 0; j < 8; ++j) o[j] = __builtin_bit_cast(unsigned short, (bf16)(v[j] * inv));
  *reinterpret_cast<u16x8*>(p + t * 8) = o;
}

// ---------------- launch ----------------
extern "C" void kernel_launch(void* const* d_in, const int* in_sizes, int n_in,
                              void* d_out, int out_size, void* d_ws, size_t ws_size,
                              hipStream_t stream) {
  const float* q = (const float*)d_in[0];
  const float* wq = (const float*)d_in[1];
  const float* wk = (const float*)d_in[2];
  const float* wv = (const float*)d_in[3];
  const float* wo = (const float*)d_in[4];
  float* out = (float*)d_out;

  constexpr int B = 4, S = 2048, D = 1024;
  constexpr long SD = (long)S * D;  // 2,097,152
  constexpr long SS = (long)S * S;  // 4,194,304
  constexpr long DD = (long)D * D;  // 1,048,576

  bf16* wsb = (bf16*)d_ws;
  bf16* qb = wsb;             // B*SD
  bf16* W3 = qb + B * SD;     // 3*DD  (wq;wk;wv stacked rows)
  bf16* wob = W3 + 3 * DD;    // DD
  bf16* Qb = wob + DD;        // B*SD
  bf16* Kb = Qb + B * SD;     // B*SD
  bf16* Vt = Kb + B * SD;     // B*SD, layout [B][D][S]
  bf16* P = Vt + B * SD;      // B*SS
  bf16* X = P + B * SS;       // B*SD, layout [B][D][S] == bugged buffer

  cvt_f32_to_bf16<<<2048, 256, 0, stream>>>(q, qb, (int)(B * SD / 4));
  cvt_f32_to_bf16<<<256, 256, 0, stream>>>(wq, W3, (int)(DD / 4));
  cvt_f32_to_bf16<<<256, 256, 0, stream>>>(wk, W3 + DD, (int)(DD / 4));
  cvt_f32_to_bf16<<<256, 256, 0, stream>>>(wv, W3 + 2 * DD, (int)(DD / 4));
  cvt_f32_to_bf16<<<256, 256, 0, stream>>>(wo, wob, (int)(DD / 4));

  // fused QKV: [8192 x 1024] @ [3072 x 1024]^T -> Qb, Kb, Vt(transposed)
  g256<3><<<dim3(12, 32, 1), 512, 0, stream>>>(qb, W3, Qb, D, 1.f, 0, 0, 0, 0);
  // scores: P[b][i][j] = Q.K/8  (per batch 2048x2048, K=1024)
  g256<0><<<dim3(8, 8, B), 512, 0, stream>>>(Qb, Kb, P, D, 0.125f, SD, SD, SS, S);
  softmax_rows<<<B * S, 256, 0, stream>>>(P);
  // PV as Xt = Vt @ P^T: C[e][i] = sum_j Vt[e][j] P[i][j]  (M=1024, N=2048, K=2048)
  // -> row-major write into X[b][e][i] (the bugged buffer), fully coalesced.
  g256<0><<<dim3(8, 4, B), 512, 0, stream>>>(Vt, P, X, S, 1.f, SD, SS, SD, S);
  // out = Xflat[8192x1024] @ wo^T -> f32
  g256<2><<<dim3(4, 32, 1), 512, 0, stream>>>(X, wob, out, D, 1.f, 0, 0, 0, D);
}

// Round 4
// 255.752 us; speedup vs baseline: 1.1043x; 1.0060x over previous
//
#include <hip/hip_runtime.h>
#include <hip/hip_bf16.h>
#include <stdint.h>

typedef __bf16 bf16;
typedef __attribute__((ext_vector_type(8))) __bf16 bf16x8;
typedef __attribute__((ext_vector_type(4))) float f32x4;
typedef __attribute__((ext_vector_type(8))) unsigned short u16x8;

#define LDS_U32 __attribute__((address_space(3))) uint32_t
#define GLB_U32 const __attribute__((address_space(1))) uint32_t
#define GLOAD16(g, l) __builtin_amdgcn_global_load_lds((GLB_U32*)(g), (LDS_U32*)(l), 16, 0, 0)

// inline-asm ds_read_b128: opaque to the compiler's waitcnt pass, so outstanding
// global_load_lds prefetches do NOT trigger a conservative vmcnt(0) drain before
// every phase's LDS reads (the round-2/3 serialization bug). Manual lgkmcnt +
// sched_barrier(0) (rule #18) provide the ordering instead.
#define DSR(dst, addr, OFFLIT) \
  asm volatile("ds_read_b128 %0, %1 offset:" OFFLIT : "=v"(dst) : "v"(addr))

// ---------------- f32 -> bf16 convert ----------------
__global__ __launch_bounds__(256) void cvt_f32_to_bf16(const float* __restrict__ src,
                                                       bf16* __restrict__ dst, int n4) {
  int i = blockIdx.x * blockDim.x + threadIdx.x;
  int stride = gridDim.x * blockDim.x;
  for (int j = i; j < n4; j += stride) {
    float4 v = reinterpret_cast<const float4*>(src)[j];
    ushort4 o;
    o.x = __builtin_bit_cast(unsigned short, (bf16)v.x);
    o.y = __builtin_bit_cast(unsigned short, (bf16)v.y);
    o.z = __builtin_bit_cast(unsigned short, (bf16)v.z);
    o.w = __builtin_bit_cast(unsigned short, (bf16)v.w);
    reinterpret_cast<ushort4*>(dst)[j] = o;
  }
}

// ================= 256x256 8-phase GEMM, C = alpha * A @ B^T =================
// Structure identical to round 3 (same LDS layout, swizzle, deep ring,
// counted vmcnt(6) boundaries); only the fragment loads are now inline-asm.
template <int EPI>
__global__ __launch_bounds__(512, 2) void g256(const bf16* __restrict__ A,
                                               const bf16* __restrict__ Bm,
                                               void* __restrict__ Cp,
                                               int K, float alpha,
                                               long sA, long sB, long sC, int ldc) {
  __shared__ bf16 smem_[65536];  // 128 KiB
  const long z = blockIdx.z;
  const int t = threadIdx.x;
  const int l = t & 63;
  const int w = t >> 6;
  const int wr = (w >> 2) * 128;  // wave row base within 256
  const int wc = (w & 3) * 64;    // wave col base within 256
  const int NT = K >> 6;

  const bf16* Ab = A + z * sA + (long)(blockIdx.y * 256) * K;
  const bf16* Bb = Bm + z * sB + (long)(blockIdx.x * 256) * K;

  // staging inverse map: thread t covers swizzled bytes [t*16, t*16+16) of one
  // 8KB 64-row unit; (r0,c0) = source row/col within the unit.
  uint32_t loc = (uint32_t)t * 16u;
  uint32_t g0 = loc ^ (((loc >> 9) & 1u) << 5);
  const int r0 = (int)(((g0 >> 10) >> 1) * 16 + ((g0 >> 6) & 15));  // 0..63
  const int c0 = (int)(((g0 >> 10) & 1) * 32 + ((g0 & 63) >> 1));   // 0..63

  // per-lane swizzled fragment read offset (bytes within the 1KB-subtile grid)
  uint32_t lo_ = (uint32_t)((l & 15) * 64 + (l >> 4) * 16);
  const uint32_t lane_off = lo_ ^ (((lo_ >> 9) & 1u) << 5);
  const uint32_t aRegion = (uint32_t)(wr >> 7) * 16384u;
  const uint32_t bRegion = 32768u + (uint32_t)(wc >> 7) * 16384u;
  const int bR0 = (wc & 64) >> 4;  // B subtile row-group base (0 or 4)
  const uint32_t smem_base = (uint32_t)(size_t)&smem_[0];

  auto STAGE1 = [&](const bf16* mat, int unit, int tile, uint32_t isB) {
    uint32_t dst = ((uint32_t)(tile & 1)) * 65536u + isB + (uint32_t)unit * 8192u + (uint32_t)t * 16u;
    const bf16* src = mat + (long)(unit * 64 + r0) * K + tile * 64 + c0;
    GLOAD16(src, smem_ + (dst >> 1));
  };

  f32x4 acc[8][4] = {};

  // ---- prologue: A(0) full, B(0) full, A(1){0,2}, B(1) full = 14 loads
  STAGE1(Ab, 0, 0, 0u); STAGE1(Ab, 1, 0, 0u); STAGE1(Ab, 2, 0, 0u); STAGE1(Ab, 3, 0, 0u);
  STAGE1(Bb, 0, 0, 32768u); STAGE1(Bb, 1, 0, 32768u); STAGE1(Bb, 2, 0, 32768u); STAGE1(Bb, 3, 0, 32768u);
  if (NT > 1) {
    STAGE1(Ab, 0, 1, 0u); STAGE1(Ab, 2, 1, 0u);
    STAGE1(Bb, 0, 1, 32768u); STAGE1(Bb, 1, 1, 32768u); STAGE1(Bb, 2, 1, 32768u); STAGE1(Bb, 3, 1, 32768u);
    asm volatile("s_waitcnt vmcnt(6)" ::: "memory");  // A(0),B(0) landed
  } else {
    asm volatile("s_waitcnt vmcnt(0)" ::: "memory");
  }
  __builtin_amdgcn_s_barrier();

#define MFMA16(ph)                                                                   \
  _Pragma("unroll") for (int mi = 0; mi < 2; ++mi)                                   \
  _Pragma("unroll") for (int n = 0; n < 4; ++n)                                      \
  _Pragma("unroll") for (int kk = 0; kk < 2; ++kk)                                   \
    acc[(ph) * 2 + mi][n] = __builtin_amdgcn_mfma_f32_16x16x32_bf16(                 \
        __builtin_bit_cast(bf16x8, aF[mi][kk]), __builtin_bit_cast(bf16x8, bF[n][kk]), \
        acc[(ph) * 2 + mi][n], 0, 0, 0);

#define PHASEX(ph, STG)                                                              \
  {                                                                                  \
    const uint32_t aP = aAddr + (ph) * 4096u;                                        \
    DSR(aF[0][0], aP, "0");    DSR(aF[0][1], aP, "1024");                            \
    DSR(aF[1][0], aP, "2048"); DSR(aF[1][1], aP, "3072");                            \
    STG                                                                              \
    __builtin_amdgcn_sched_barrier(0);                                               \
    __builtin_amdgcn_s_barrier();                                                    \
    asm volatile("s_waitcnt lgkmcnt(0)" ::: "memory");                               \
    __builtin_amdgcn_sched_barrier(0);                                               \
    __builtin_amdgcn_s_setprio(1);                                                   \
    MFMA16(ph)                                                                       \
    __builtin_amdgcn_s_setprio(0);                                                   \
  }

  for (int T = 0; T < NT; ++T) {
    const uint32_t pb = smem_base + (uint32_t)(T & 1) * 65536u;
    const uint32_t aAddr = pb + aRegion + lane_off;
    const uint32_t bAddr = pb + bRegion + (uint32_t)bR0 * 2048u + lane_off;
    f32x4 bF[4][2];
    f32x4 aF[2][2];

    // ---------- phase 0: all bF (8 reads) + aF quad0 (4); stage A(T+1){1,3} ----------
    DSR(bF[0][0], bAddr, "0");    DSR(bF[0][1], bAddr, "1024");
    DSR(bF[1][0], bAddr, "2048"); DSR(bF[1][1], bAddr, "3072");
    DSR(bF[2][0], bAddr, "4096"); DSR(bF[2][1], bAddr, "5120");
    DSR(bF[3][0], bAddr, "6144"); DSR(bF[3][1], bAddr, "7168");
    DSR(aF[0][0], aAddr, "0");    DSR(aF[0][1], aAddr, "1024");
    DSR(aF[1][0], aAddr, "2048"); DSR(aF[1][1], aAddr, "3072");
    if (T + 1 < NT) { STAGE1(Ab, 1, T + 1, 0u); STAGE1(Ab, 3, T + 1, 0u); }
    __builtin_amdgcn_sched_barrier(0);
    asm volatile("s_waitcnt lgkmcnt(8)" ::: "memory");
    __builtin_amdgcn_s_barrier();
    asm volatile("s_waitcnt lgkmcnt(0)" ::: "memory");
    __builtin_amdgcn_sched_barrier(0);
    __builtin_amdgcn_s_setprio(1);
    MFMA16(0)
    __builtin_amdgcn_s_setprio(0);
    __builtin_amdgcn_s_barrier();

    // ---------- phase 1 ----------
    PHASEX(1, if (T + 2 < NT) { STAGE1(Bb, 0, T + 2, 32768u); STAGE1(Bb, 1, T + 2, 32768u); })
    __builtin_amdgcn_s_barrier();
    // ---------- phase 2 ----------
    PHASEX(2, if (T + 2 < NT) { STAGE1(Ab, 0, T + 2, 0u); STAGE1(Ab, 2, T + 2, 0u); })
    __builtin_amdgcn_s_barrier();
    // ---------- phase 3 + boundary ----------
    PHASEX(3, if (T + 2 < NT) { STAGE1(Bb, 2, T + 2, 32768u); STAGE1(Bb, 3, T + 2, 32768u); })
    if (T + 2 < NT) asm volatile("s_waitcnt vmcnt(6)" ::: "memory");
    else            asm volatile("s_waitcnt vmcnt(0)" ::: "memory");
    __builtin_amdgcn_s_barrier();
  }
#undef PHASEX
#undef MFMA16

  // ---- epilogue: C/D layout col = lane&15, row = (lane>>4)*4 + i
  const int orow0 = blockIdx.y * 256 + wr + (l >> 4) * 4;
  const int ocol0 = blockIdx.x * 256 + wc + (l & 15);
#pragma unroll
  for (int m = 0; m < 8; ++m)
#pragma unroll
    for (int n = 0; n < 4; ++n)
#pragma unroll
      for (int i = 0; i < 4; ++i) {
        const long r = orow0 + m * 16 + i;
        const long c = ocol0 + n * 16;
        const float v = acc[m][n][i] * alpha;
        if constexpr (EPI == 0) {
          ((bf16*)Cp)[z * sC + r * ldc + c] = (bf16)v;
        } else if constexpr (EPI == 2) {
          ((float*)Cp)[r * ldc + c] = v;
        } else {
          // fused QKV epilogue: rows r = b*2048+s in [0,8192); cols c in [0,3072)
          bf16* Qb = (bf16*)Cp;
          bf16* Kb = Qb + 8388608;  // 8192*1024
          bf16* Vt = Kb + 8388608;
          if (c < 1024) Qb[r * 1024 + c] = (bf16)v;
          else if (c < 2048) Kb[r * 1024 + (c - 1024)] = (bf16)v;
          else Vt[(r >> 11) * 2097152 + (c - 2048) * 2048 + (r & 2047)] = (bf16)v;
        }
      }
}

// ---------------- row softmax, in place, rows of 2048 bf16 ----------------
__global__ __launch_bounds__(256) void softmax_rows(bf16* __restrict__ P) {
  const long row = blockIdx.x;
  bf16* p = P + row * 2048;
  const int t = threadIdx.x;
  const int lane = t & 63;
  const int wave = t >> 6;

  u16x8 raw = *reinterpret_cast<const u16x8*>(p + t * 8);
  float v[8];
#pragma unroll
  for (int j = 0; j < 8; ++j) {
    uint32_t bits = ((uint32_t)raw[j]) << 16;
    v[j] = __builtin_bit_cast(float, bits);
  }
  float m = v[0];
#pragma unroll
  for (int j = 1; j < 8; ++j) m = fmaxf(m, v[j]);
#pragma unroll
  for (int off = 32; off > 0; off >>= 1) m = fmaxf(m, __shfl_xor(m, off, 64));
  __shared__ float redm[4];
  __shared__ float reds[4];
  if (lane == 0) redm[wave] = m;
  __syncthreads();
  m = fmaxf(fmaxf(redm[0], redm[1]), fmaxf(redm[2], redm[3]));

  float s = 0.f;
#pragma unroll
  for (int j = 0; j < 8; ++j) {
    v[j] = __expf(v[j] - m);
    s += v[j];
  }
#pragma unroll
  for (int off = 32; off > 0; off >>= 1) s += __shfl_xor(s, off, 64);
  if (lane == 0) reds[wave] = s;
  __syncthreads();
  s = reds[0] + reds[1] + reds[2] + reds[3];
  const float inv = 1.f / s;

  u16x8 o;
#pragma unroll
  for (int j = 0; j < 8; ++j) o[j] = __builtin_bit_cast(unsigned short, (bf16)(v[j] * inv));
  *reinterpret_cast<u16x8*>(p + t * 8) = o;
}

// ---------------- launch ----------------
extern "C" void kernel_launch(void* const* d_in, const int* in_sizes, int n_in,
                              void* d_out, int out_size, void* d_ws, size_t ws_size,
                              hipStream_t stream) {
  const float* q = (const float*)d_in[0];
  const float* wq = (const float*)d_in[1];
  const float* wk = (const float*)d_in[2];
  const float* wv = (const float*)d_in[3];
  const float* wo = (const float*)d_in[4];
  float* out = (float*)d_out;

  constexpr int B = 4, S = 2048, D = 1024;
  constexpr long SD = (long)S * D;  // 2,097,152
  constexpr long SS = (long)S * S;  // 4,194,304
  constexpr long DD = (long)D * D;  // 1,048,576

  bf16* wsb = (bf16*)d_ws;
  bf16* qb = wsb;             // B*SD
  bf16* W3 = qb + B * SD;     // 3*DD  (wq;wk;wv stacked rows)
  bf16* wob = W3 + 3 * DD;    // DD
  bf16* Qb = wob + DD;        // B*SD
  bf16* Kb = Qb + B * SD;     // B*SD
  bf16* Vt = Kb + B * SD;     // B*SD, layout [B][D][S]
  bf16* P = Vt + B * SD;      // B*SS
  bf16* X = P + B * SS;       // B*SD, layout [B][D][S] == bugged buffer

  cvt_f32_to_bf16<<<2048, 256, 0, stream>>>(q, qb, (int)(B * SD / 4));
  cvt_f32_to_bf16<<<256, 256, 0, stream>>>(wq, W3, (int)(DD / 4));
  cvt_f32_to_bf16<<<256, 256, 0, stream>>>(wk, W3 + DD, (int)(DD / 4));
  cvt_f32_to_bf16<<<256, 256, 0, stream>>>(wv, W3 + 2 * DD, (int)(DD / 4));
  cvt_f32_to_bf16<<<256, 256, 0, stream>>>(wo, wob, (int)(DD / 4));

  // fused QKV: [8192 x 1024] @ [3072 x 1024]^T -> Qb, Kb, Vt(transposed)
  g256<3><<<dim3(12, 32, 1), 512, 0, stream>>>(qb, W3, Qb, D, 1.f, 0, 0, 0, 0);
  // scores: P[b][i][j] = Q.K/8  (per batch 2048x2048, K=1024)
  g256<0><<<dim3(8, 8, B), 512, 0, stream>>>(Qb, Kb, P, D, 0.125f, SD, SD, SS, S);
  softmax_rows<<<B * S, 256, 0, stream>>>(P);
  // PV as Xt = Vt @ P^T: C[e][i] = sum_j Vt[e][j] P[i][j]  (M=1024, N=2048, K=2048)
  g256<0><<<dim3(8, 4, B), 512, 0, stream>>>(Vt, P, X, S, 1.f, SD, SS, SD, S);
  // out = Xflat[8192x1024] @ wo^T -> f32
  g256<2><<<dim3(4, 32, 1), 512, 0, stream>>>(X, wob, out, D, 1.f, 0, 0, 0, D);
}

// Round 5
// 255.628 us; speedup vs baseline: 1.1048x; 1.0005x over previous
//
#include <hip/hip_runtime.h>
#include <hip/hip_bf16.h>
#include <stdint.h>

typedef __bf16 bf16;
typedef __attribute__((ext_vector_type(8))) __bf16 bf16x8;
typedef __attribute__((ext_vector_type(4))) float f32x4;
typedef __attribute__((ext_vector_type(8))) unsigned short u16x8;

#define LDS_U32 __attribute__((address_space(3))) uint32_t
#define GLB_U32 const __attribute__((address_space(1))) uint32_t
#define GLOAD16(g, l) __builtin_amdgcn_global_load_lds((GLB_U32*)(g), (LDS_U32*)(l), 16, 0, 0)

// Volatile inline-asm ds_read (no "memory" clobber!): opaque to alias analysis
// AND does not trigger SIInsertWaitcnts' conservative vmcnt(0) drain. Ordering
// vs MFMA is provided by explicit lgkmcnt + sched_barrier(0) (rule #18).
#define DSR(dst, addr, OFFLIT) \
  asm volatile("ds_read_b128 %0, %1 offset:" OFFLIT : "=v"(dst) : "v"(addr))

// Bare waitcnt asms — NO "memory" clobber. A "memory" clobber makes the
// backend's waitcnt pass treat the asm as a memory op and prepend a full
// s_waitcnt vmcnt(0) drain => serialized every phase (rounds 2-4 bug).
#define WAIT_LGKM0() asm volatile("s_waitcnt lgkmcnt(0)")
#define WAIT_LGKM8() asm volatile("s_waitcnt lgkmcnt(8)")
#define WAIT_VM(n)   asm volatile("s_waitcnt vmcnt(" #n ")")

// ---------------- f32 -> bf16 convert ----------------
__global__ __launch_bounds__(256) void cvt_f32_to_bf16(const float* __restrict__ src,
                                                       bf16* __restrict__ dst, int n4) {
  int i = blockIdx.x * blockDim.x + threadIdx.x;
  int stride = gridDim.x * blockDim.x;
  for (int j = i; j < n4; j += stride) {
    float4 v = reinterpret_cast<const float4*>(src)[j];
    ushort4 o;
    o.x = __builtin_bit_cast(unsigned short, (bf16)v.x);
    o.y = __builtin_bit_cast(unsigned short, (bf16)v.y);
    o.z = __builtin_bit_cast(unsigned short, (bf16)v.z);
    o.w = __builtin_bit_cast(unsigned short, (bf16)v.w);
    reinterpret_cast<ushort4*>(dst)[j] = o;
  }
}

// ================= 256x256 8-phase GEMM, C = alpha * A @ B^T =================
// Structure identical to round 4; only the waitcnt asms lost their "memory"
// clobbers (and the boundary wait gained sched_barrier pins).
template <int EPI>
__global__ __launch_bounds__(512, 2) void g256(const bf16* __restrict__ A,
                                               const bf16* __restrict__ Bm,
                                               void* __restrict__ Cp,
                                               int K, float alpha,
                                               long sA, long sB, long sC, int ldc) {
  __shared__ bf16 smem_[65536];  // 128 KiB
  const long z = blockIdx.z;
  const int t = threadIdx.x;
  const int l = t & 63;
  const int w = t >> 6;
  const int wr = (w >> 2) * 128;  // wave row base within 256
  const int wc = (w & 3) * 64;    // wave col base within 256
  const int NT = K >> 6;

  const bf16* Ab = A + z * sA + (long)(blockIdx.y * 256) * K;
  const bf16* Bb = Bm + z * sB + (long)(blockIdx.x * 256) * K;

  // staging inverse map: thread t covers swizzled bytes [t*16, t*16+16) of one
  // 8KB 64-row unit; (r0,c0) = source row/col within the unit.
  uint32_t loc = (uint32_t)t * 16u;
  uint32_t g0 = loc ^ (((loc >> 9) & 1u) << 5);
  const int r0 = (int)(((g0 >> 10) >> 1) * 16 + ((g0 >> 6) & 15));  // 0..63
  const int c0 = (int)(((g0 >> 10) & 1) * 32 + ((g0 & 63) >> 1));   // 0..63

  // per-lane swizzled fragment read offset (bytes within the 1KB-subtile grid)
  uint32_t lo_ = (uint32_t)((l & 15) * 64 + (l >> 4) * 16);
  const uint32_t lane_off = lo_ ^ (((lo_ >> 9) & 1u) << 5);
  const uint32_t aRegion = (uint32_t)(wr >> 7) * 16384u;
  const uint32_t bRegion = 32768u + (uint32_t)(wc >> 7) * 16384u;
  const int bR0 = (wc & 64) >> 4;  // B subtile row-group base (0 or 4)
  const uint32_t smem_base = (uint32_t)(size_t)&smem_[0];

  auto STAGE1 = [&](const bf16* mat, int unit, int tile, uint32_t isB) {
    uint32_t dst = ((uint32_t)(tile & 1)) * 65536u + isB + (uint32_t)unit * 8192u + (uint32_t)t * 16u;
    const bf16* src = mat + (long)(unit * 64 + r0) * K + tile * 64 + c0;
    GLOAD16(src, smem_ + (dst >> 1));
  };

  f32x4 acc[8][4] = {};

  // ---- prologue: A(0) full, B(0) full, A(1){0,2}, B(1) full = 14 loads
  STAGE1(Ab, 0, 0, 0u); STAGE1(Ab, 1, 0, 0u); STAGE1(Ab, 2, 0, 0u); STAGE1(Ab, 3, 0, 0u);
  STAGE1(Bb, 0, 0, 32768u); STAGE1(Bb, 1, 0, 32768u); STAGE1(Bb, 2, 0, 32768u); STAGE1(Bb, 3, 0, 32768u);
  if (NT > 1) {
    STAGE1(Ab, 0, 1, 0u); STAGE1(Ab, 2, 1, 0u);
    STAGE1(Bb, 0, 1, 32768u); STAGE1(Bb, 1, 1, 32768u); STAGE1(Bb, 2, 1, 32768u); STAGE1(Bb, 3, 1, 32768u);
    __builtin_amdgcn_sched_barrier(0);
    WAIT_VM(6);  // A(0),B(0) landed
  } else {
    __builtin_amdgcn_sched_barrier(0);
    WAIT_VM(0);
  }
  __builtin_amdgcn_s_barrier();

#define MFMA16(ph)                                                                   \
  _Pragma("unroll") for (int mi = 0; mi < 2; ++mi)                                   \
  _Pragma("unroll") for (int n = 0; n < 4; ++n)                                      \
  _Pragma("unroll") for (int kk = 0; kk < 2; ++kk)                                   \
    acc[(ph) * 2 + mi][n] = __builtin_amdgcn_mfma_f32_16x16x32_bf16(                 \
        __builtin_bit_cast(bf16x8, aF[mi][kk]), __builtin_bit_cast(bf16x8, bF[n][kk]), \
        acc[(ph) * 2 + mi][n], 0, 0, 0);

#define PHASEX(ph, STG)                                                              \
  {                                                                                  \
    const uint32_t aP = aAddr + (ph) * 4096u;                                        \
    DSR(aF[0][0], aP, "0");    DSR(aF[0][1], aP, "1024");                            \
    DSR(aF[1][0], aP, "2048"); DSR(aF[1][1], aP, "3072");                            \
    STG                                                                              \
    __builtin_amdgcn_sched_barrier(0);                                               \
    __builtin_amdgcn_s_barrier();                                                    \
    WAIT_LGKM0();                                                                    \
    __builtin_amdgcn_sched_barrier(0);                                               \
    __builtin_amdgcn_s_setprio(1);                                                   \
    MFMA16(ph)                                                                       \
    __builtin_amdgcn_s_setprio(0);                                                   \
  }

  for (int T = 0; T < NT; ++T) {
    const uint32_t pb = smem_base + (uint32_t)(T & 1) * 65536u;
    const uint32_t aAddr = pb + aRegion + lane_off;
    const uint32_t bAddr = pb + bRegion + (uint32_t)bR0 * 2048u + lane_off;
    f32x4 bF[4][2];
    f32x4 aF[2][2];

    // ---------- phase 0: all bF (8 reads) + aF quad0 (4); stage A(T+1){1,3} ----------
    DSR(bF[0][0], bAddr, "0");    DSR(bF[0][1], bAddr, "1024");
    DSR(bF[1][0], bAddr, "2048"); DSR(bF[1][1], bAddr, "3072");
    DSR(bF[2][0], bAddr, "4096"); DSR(bF[2][1], bAddr, "5120");
    DSR(bF[3][0], bAddr, "6144"); DSR(bF[3][1], bAddr, "7168");
    DSR(aF[0][0], aAddr, "0");    DSR(aF[0][1], aAddr, "1024");
    DSR(aF[1][0], aAddr, "2048"); DSR(aF[1][1], aAddr, "3072");
    if (T + 1 < NT) { STAGE1(Ab, 1, T + 1, 0u); STAGE1(Ab, 3, T + 1, 0u); }
    __builtin_amdgcn_sched_barrier(0);
    WAIT_LGKM8();
    __builtin_amdgcn_s_barrier();
    WAIT_LGKM0();
    __builtin_amdgcn_sched_barrier(0);
    __builtin_amdgcn_s_setprio(1);
    MFMA16(0)
    __builtin_amdgcn_s_setprio(0);
    __builtin_amdgcn_s_barrier();

    // ---------- phase 1 ----------
    PHASEX(1, if (T + 2 < NT) { STAGE1(Bb, 0, T + 2, 32768u); STAGE1(Bb, 1, T + 2, 32768u); })
    __builtin_amdgcn_s_barrier();
    // ---------- phase 2 ----------
    PHASEX(2, if (T + 2 < NT) { STAGE1(Ab, 0, T + 2, 0u); STAGE1(Ab, 2, T + 2, 0u); })
    __builtin_amdgcn_s_barrier();
    // ---------- phase 3 + boundary ----------
    PHASEX(3, if (T + 2 < NT) { STAGE1(Bb, 2, T + 2, 32768u); STAGE1(Bb, 3, T + 2, 32768u); })
    __builtin_amdgcn_sched_barrier(0);
    if (T + 2 < NT) { WAIT_VM(6); } else { WAIT_VM(0); }
    __builtin_amdgcn_sched_barrier(0);
    __builtin_amdgcn_s_barrier();
  }
#undef PHASEX
#undef MFMA16

  // ---- epilogue: C/D layout col = lane&15, row = (lane>>4)*4 + i
  const int orow0 = blockIdx.y * 256 + wr + (l >> 4) * 4;
  const int ocol0 = blockIdx.x * 256 + wc + (l & 15);
#pragma unroll
  for (int m = 0; m < 8; ++m)
#pragma unroll
    for (int n = 0; n < 4; ++n)
#pragma unroll
      for (int i = 0; i < 4; ++i) {
        const long r = orow0 + m * 16 + i;
        const long c = ocol0 + n * 16;
        const float v = acc[m][n][i] * alpha;
        if constexpr (EPI == 0) {
          ((bf16*)Cp)[z * sC + r * ldc + c] = (bf16)v;
        } else if constexpr (EPI == 2) {
          ((float*)Cp)[r * ldc + c] = v;
        } else {
          // fused QKV epilogue: rows r = b*2048+s in [0,8192); cols c in [0,3072)
          bf16* Qb = (bf16*)Cp;
          bf16* Kb = Qb + 8388608;  // 8192*1024
          bf16* Vt = Kb + 8388608;
          if (c < 1024) Qb[r * 1024 + c] = (bf16)v;
          else if (c < 2048) Kb[r * 1024 + (c - 1024)] = (bf16)v;
          else Vt[(r >> 11) * 2097152 + (c - 2048) * 2048 + (r & 2047)] = (bf16)v;
        }
      }
}

// ---------------- row softmax, in place, rows of 2048 bf16 ----------------
__global__ __launch_bounds__(256) void softmax_rows(bf16* __restrict__ P) {
  const long row = blockIdx.x;
  bf16* p = P + row * 2048;
  const int t = threadIdx.x;
  const int lane = t & 63;
  const int wave = t >> 6;

  u16x8 raw = *reinterpret_cast<const u16x8*>(p + t * 8);
  float v[8];
#pragma unroll
  for (int j = 0; j < 8; ++j) {
    uint32_t bits = ((uint32_t)raw[j]) << 16;
    v[j] = __builtin_bit_cast(float, bits);
  }
  float m = v[0];
#pragma unroll
  for (int j = 1; j < 8; ++j) m = fmaxf(m, v[j]);
#pragma unroll
  for (int off = 32; off > 0; off >>= 1) m = fmaxf(m, __shfl_xor(m, off, 64));
  __shared__ float redm[4];
  __shared__ float reds[4];
  if (lane == 0) redm[wave] = m;
  __syncthreads();
  m = fmaxf(fmaxf(redm[0], redm[1]), fmaxf(redm[2], redm[3]));

  float s = 0.f;
#pragma unroll
  for (int j = 0; j < 8; ++j) {
    v[j] = __expf(v[j] - m);
    s += v[j];
  }
#pragma unroll
  for (int off = 32; off > 0; off >>= 1) s += __shfl_xor(s, off, 64);
  if (lane == 0) reds[wave] = s;
  __syncthreads();
  s = reds[0] + reds[1] + reds[2] + reds[3];
  const float inv = 1.f / s;

  u16x8 o;
#pragma unroll
  for (int j = 0; j < 8; ++j) o[j] = __builtin_bit_cast(unsigned short, (bf16)(v[j] * inv));
  *reinterpret_cast<u16x8*>(p + t * 8) = o;
}

// ---------------- launch ----------------
extern "C" void kernel_launch(void* const* d_in, const int* in_sizes, int n_in,
                              void* d_out, int out_size, void* d_ws, size_t ws_size,
                              hipStream_t stream) {
  const float* q = (const float*)d_in[0];
  const float* wq = (const float*)d_in[1];
  const float* wk = (const float*)d_in[2];
  const float* wv = (const float*)d_in[3];
  const float* wo = (const float*)d_in[4];
  float* out = (float*)d_out;

  constexpr int B = 4, S = 2048, D = 1024;
  constexpr long SD = (long)S * D;  // 2,097,152
  constexpr long SS = (long)S * S;  // 4,194,304
  constexpr long DD = (long)D * D;  // 1,048,576

  bf16* wsb = (bf16*)d_ws;
  bf16* qb = wsb;             // B*SD
  bf16* W3 = qb + B * SD;     // 3*DD  (wq;wk;wv stacked rows)
  bf16* wob = W3 + 3 * DD;    // DD
  bf16* Qb = wob + DD;        // B*SD
  bf16* Kb = Qb + B * SD;     // B*SD
  bf16* Vt = Kb + B * SD;     // B*SD, layout [B][D][S]
  bf16* P = Vt + B * SD;      // B*SS
  bf16* X = P + B * SS;       // B*SD, layout [B][D][S] == bugged buffer

  cvt_f32_to_bf16<<<2048, 256, 0, stream>>>(q, qb, (int)(B * SD / 4));
  cvt_f32_to_bf16<<<256, 256, 0, stream>>>(wq, W3, (int)(DD / 4));
  cvt_f32_to_bf16<<<256, 256, 0, stream>>>(wk, W3 + DD, (int)(DD / 4));
  cvt_f32_to_bf16<<<256, 256, 0, stream>>>(wv, W3 + 2 * DD, (int)(DD / 4));
  cvt_f32_to_bf16<<<256, 256, 0, stream>>>(wo, wob, (int)(DD / 4));

  // fused QKV: [8192 x 1024] @ [3072 x 1024]^T -> Qb, Kb, Vt(transposed)
  g256<3><<<dim3(12, 32, 1), 512, 0, stream>>>(qb, W3, Qb, D, 1.f, 0, 0, 0, 0);
  // scores: P[b][i][j] = Q.K/8  (per batch 2048x2048, K=1024)
  g256<0><<<dim3(8, 8, B), 512, 0, stream>>>(Qb, Kb, P, D, 0.125f, SD, SD, SS, S);
  softmax_rows<<<B * S, 256, 0, stream>>>(P);
  // PV as Xt = Vt @ P^T: C[e][i] = sum_j Vt[e][j] P[i][j]  (M=1024, N=2048, K=2048)
  g256<0><<<dim3(8, 4, B), 512, 0, stream>>>(Vt, P, X, S, 1.f, SD, SS, SD, S);
  // out = Xflat[8192x1024] @ wo^T -> f32
  g256<2><<<dim3(4, 32, 1), 512, 0, stream>>>(X, wob, out, D, 1.f, 0, 0, 0, D);
}